// Round 13
// baseline (161.183 us; speedup 1.0000x reference)
//
#include <hip/hip_runtime.h>
#include <hip/hip_bf16.h>

typedef short bf16x8 __attribute__((ext_vector_type(8)));
typedef short bf16x4 __attribute__((ext_vector_type(4)));
typedef float f32x4 __attribute__((ext_vector_type(4)));

#define T_DIM 2048
#define D_DIM 64
#define WIN 128
#define QBLK 64
#define ACCT 17          // max live 16-wide k-tiles per 16-row wave tile
#define NEGBIG -1e30f

__device__ __forceinline__ short f2b(float x) {
  __hip_bfloat16 h = __float2bfloat16(x);
  return *reinterpret_cast<short*>(&h);
}
__device__ __forceinline__ float b2f(short s) {
  unsigned u = ((unsigned)(unsigned short)s) << 16;
  return __builtin_bit_cast(float, u);
}
__device__ __forceinline__ bf16x8 cvt8(f32x4 a, f32x4 b) {
  bf16x8 r;
  r[0] = f2b(a[0]); r[1] = f2b(a[1]); r[2] = f2b(a[2]); r[3] = f2b(a[3]);
  r[4] = f2b(b[0]); r[5] = f2b(b[1]); r[6] = f2b(b[2]); r[7] = f2b(b[3]);
  return r;
}
// swizzled byte address in a 640B-row LDS tile
__device__ __forceinline__ int swz(int row, int b) { return row * 640 + (b ^ ((row & 7) << 4)); }

// ---------------- pure zero-fill of out-of-band attn (fill-kernel clone) ----------------
__global__ __launch_bounds__(256) void lsa_zero(float* __restrict__ Ag) {
  const int tid = threadIdx.x;
  const int q0 = (blockIdx.x & 31) * QBLK;
  const int bh = blockIdx.x >> 5;
  int kstart = q0 - WIN; if (kstart < 0) kstart = 0;
  int kend = q0 + QBLK + WIN; if (kend > T_DIM) kend = T_DIM;
  const f32x4 z = {0.f, 0.f, 0.f, 0.f};
  float* arow = Ag + (size_t)bh * ((size_t)T_DIM * T_DIM) + (size_t)q0 * T_DIM;
  for (int r = 0; r < QBLK; ++r, arow += T_DIM) {
    for (int c = tid * 4; c < kstart; c += 1024)
      __builtin_nontemporal_store(z, (f32x4*)(arow + c));
    for (int c = kend + tid * 4; c < T_DIM; c += 1024)
      __builtin_nontemporal_store(z, (f32x4*)(arow + c));
  }
}

// ---------------- banded attention: band + O only ----------------
__global__ __launch_bounds__(256, 2) void lsa_attn(
    const float* __restrict__ Qg, const float* __restrict__ Kg,
    const float* __restrict__ Vg, float* __restrict__ Og,
    float* __restrict__ Ag) {
  const int tid = threadIdx.x;
  // XCD-chunked swizzle: XCD x hosts works [128x,128x+128) = 4 bh, 32 q-blocks
  const int work = ((blockIdx.x & 7) << 7) + (blockIdx.x >> 3);
  const int bh = work >> 5;
  const int q0 = (work & 31) * QBLK;
  int kstart = q0 - WIN; if (kstart < 0) kstart = 0;
  int kend = q0 + QBLK + WIN; if (kend > T_DIM) kend = T_DIM;
  const int KW = kend - kstart;   // 192/256/320
  const int nkt = KW >> 4;

  const float* qptr = Qg + (size_t)bh * (T_DIM * D_DIM);
  const float* kptr = Kg + (size_t)bh * (T_DIM * D_DIM);
  const float* vptr = Vg + (size_t)bh * (T_DIM * D_DIM);
  float* optr = Og + (size_t)bh * (T_DIM * D_DIM);
  float* aptr = Ag + (size_t)bh * ((size_t)T_DIM * T_DIM);

  // LDS: Vt 40KB + P band 40KB = 80KB -> 2 blocks/CU
  __shared__ __align__(16) char Vb[D_DIM * 640];
  __shared__ __align__(16) char Pb[QBLK * 640];

  // ---- stage V transposed: Vt[d][k] bf16 (consumed after the only barrier) ----
  for (int idx = tid; idx < KW * 16; idx += 256) {
    const int r = idx >> 4, c4 = idx & 15;
    f32x4 f = *(const f32x4*)(vptr + (size_t)(kstart + r) * D_DIM + c4 * 4);
    const int d0 = c4 * 4;
    *(short*)(Vb + swz(d0 + 0, r * 2)) = f2b(f[0]);
    *(short*)(Vb + swz(d0 + 1, r * 2)) = f2b(f[1]);
    *(short*)(Vb + swz(d0 + 2, r * 2)) = f2b(f[2]);
    *(short*)(Vb + swz(d0 + 3, r * 2)) = f2b(f[3]);
  }

  const int lane = tid & 63, w = tid >> 6, c = lane & 15, hi = lane >> 4;

  // Q B-frag (swapped QK^T): lane holds Q row q0+w*16+c, d-slices
  const float* qrow = qptr + (size_t)(q0 + w * 16 + c) * D_DIM + 8 * hi;
  const bf16x8 qb0 = cvt8(*(const f32x4*)qrow, *(const f32x4*)(qrow + 4));
  const bf16x8 qb1 = cvt8(*(const f32x4*)(qrow + 32), *(const f32x4*)(qrow + 36));

  // per-wave live tile range
  int klo = q0 + w * 16 - WIN - kstart; if (klo < 0) klo = 0;
  const int kt0 = klo >> 4;
  int kt1 = (q0 + w * 16 + 15 + WIN + 1 - kstart + 15) >> 4; if (kt1 > nkt) kt1 = nkt;
  const int s0 = kt0 >> 1, s1 = (kt1 + 1) >> 1;
  const int nlive = kt1 - kt0;

  // ---- S^T = K Q^T over live tiles: lane (c,hi) owns q-row c, k = 16i+4hi+j ----
  f32x4 acc[ACCT];
#pragma unroll
  for (int i = 0; i < ACCT; ++i) {
    acc[i] = (f32x4){0.f, 0.f, 0.f, 0.f};
    if (i < nlive) {
      const float* kr = kptr + (size_t)(kstart + (kt0 + i) * 16 + c) * D_DIM + 8 * hi;
      const bf16x8 b0 = cvt8(*(const f32x4*)kr, *(const f32x4*)(kr + 4));
      const bf16x8 b1 = cvt8(*(const f32x4*)(kr + 32), *(const f32x4*)(kr + 36));
      acc[i] = __builtin_amdgcn_mfma_f32_16x16x32_bf16(b0, qb0, acc[i], 0, 0, 0);
      acc[i] = __builtin_amdgcn_mfma_f32_16x16x32_bf16(b1, qb1, acc[i], 0, 0, 0);
    }
  }

  // ---- softmax: in-lane over 68 values, then 2 shfls across hi-groups ----
  const int qr = q0 + w * 16 + c;            // this lane's q-row
  const int kb = kstart + 4 * hi;
  float m = NEGBIG;
#pragma unroll
  for (int i = 0; i < ACCT; ++i)
    if (i < nlive) {
#pragma unroll
      for (int j = 0; j < 4; ++j) {
        float s = acc[i][j] * 0.125f;        // 1/sqrt(64)
        const int kcol = kb + (kt0 + i) * 16 + j;
        int dist = qr - kcol; dist = dist < 0 ? -dist : dist;
        s = (dist <= WIN) ? s : NEGBIG;
        acc[i][j] = s;
        m = fmaxf(m, s);
      }
    }
  m = fmaxf(m, __shfl_xor(m, 16));
  m = fmaxf(m, __shfl_xor(m, 32));
  float sum = 0.f;
#pragma unroll
  for (int i = 0; i < ACCT; ++i)
    if (i < nlive) {
#pragma unroll
      for (int j = 0; j < 4; ++j) {
        const float p = __expf(acc[i][j] - m);
        acc[i][j] = p;
        sum += p;
      }
    }
  sum += __shfl_xor(sum, 16);
  sum += __shfl_xor(sum, 32);
  const float inv = 1.f / sum;

  // ---- P(bf16) -> Pb: one ds_write_b64 per live tile ----
  const int prow = w * 16 + c;
#pragma unroll
  for (int i = 0; i < ACCT; ++i)
    if (i < nlive) {
      bf16x4 pk;
#pragma unroll
      for (int j = 0; j < 4; ++j) pk[j] = f2b(acc[i][j] * inv);
      *(bf16x4*)(Pb + swz(prow, 32 * (kt0 + i) + 8 * hi)) = pk;
    }
  {
    const bf16x4 z4 = {0, 0, 0, 0};
    for (int t = 0; t < kt0; ++t) *(bf16x4*)(Pb + swz(prow, 32 * t + 8 * hi)) = z4;
    for (int t = kt1; t < nkt; ++t) *(bf16x4*)(Pb + swz(prow, 32 * t + 8 * hi)) = z4;
  }

  // ---- band sweep: KW cols per row, contiguous nt stores from Pb ----
  for (int rr = 0; rr < 16; ++rr) {
    const int r = w * 16 + rr;
    float* dst = aptr + (size_t)(q0 + r) * T_DIM + kstart;
#pragma unroll
    for (int i = 0; i < 2; ++i) {
      const int off = i * 256 + lane * 4;
      if (off < KW) {
        const bf16x4 pv = *(const bf16x4*)(Pb + swz(r, off * 2));
        f32x4 val;
        val[0] = b2f(pv[0]); val[1] = b2f(pv[1]); val[2] = b2f(pv[2]); val[3] = b2f(pv[3]);
        __builtin_nontemporal_store(val, (f32x4*)(dst + off));
      }
    }
  }

  __syncthreads();   // only barrier: Vt ready for PV

  // ---- O = P V ----
  f32x4 ov[4];
#pragma unroll
  for (int dt = 0; dt < 4; ++dt) ov[dt] = (f32x4){0.f, 0.f, 0.f, 0.f};
  for (int s = s0; s < s1; ++s) {
    const bf16x8 pa = *(const bf16x8*)(Pb + swz(w * 16 + c, 64 * s + 16 * hi));
#pragma unroll
    for (int dt = 0; dt < 4; ++dt) {
      const bf16x8 vb = *(const bf16x8*)(Vb + swz(dt * 16 + c, 64 * s + 16 * hi));
      ov[dt] = __builtin_amdgcn_mfma_f32_16x16x32_bf16(pa, vb, ov[dt], 0, 0, 0);
    }
  }
#pragma unroll
  for (int dt = 0; dt < 4; ++dt)
#pragma unroll
    for (int j = 0; j < 4; ++j)
      __builtin_nontemporal_store(
          ov[dt][j], optr + (size_t)(q0 + w * 16 + 4 * hi + j) * D_DIM + dt * 16 + c);
}

extern "C" void kernel_launch(void* const* d_in, const int* in_sizes, int n_in,
                              void* d_out, int out_size, void* d_ws, size_t ws_size,
                              hipStream_t stream) {
  const float* q = (const float*)d_in[0];
  const float* k = (const float*)d_in[1];
  const float* v = (const float*)d_in[2];
  float* out = (float*)d_out;
  float* attn = out + (size_t)2 * 16 * T_DIM * D_DIM;  // output first, then attn
  lsa_attn<<<dim3(2 * 16 * (T_DIM / QBLK)), dim3(256), 0, stream>>>(q, k, v, out, attn);
  lsa_zero<<<dim3(2 * 16 * (T_DIM / QBLK)), dim3(256), 0, stream>>>(attn);
}

// Round 14
// 126.869 us; speedup vs baseline: 1.2705x; 1.2705x over previous
//
#include <hip/hip_runtime.h>
#include <hip/hip_bf16.h>

typedef short bf16x8 __attribute__((ext_vector_type(8)));
typedef short bf16x4 __attribute__((ext_vector_type(4)));
typedef float f32x4 __attribute__((ext_vector_type(4)));

#define T_DIM 2048
#define D_DIM 64
#define WIN 128
#define QBLK 64
#define ACCT 17          // max live 16-wide k-tiles per 16-row wave tile
#define NEGBIG -1e30f

__device__ __forceinline__ short f2b(float x) {
  __hip_bfloat16 h = __float2bfloat16(x);
  return *reinterpret_cast<short*>(&h);
}
__device__ __forceinline__ float b2f(short s) {
  unsigned u = ((unsigned)(unsigned short)s) << 16;
  return __builtin_bit_cast(float, u);
}
__device__ __forceinline__ bf16x8 cvt8(f32x4 a, f32x4 b) {
  bf16x8 r;
  r[0] = f2b(a[0]); r[1] = f2b(a[1]); r[2] = f2b(a[2]); r[3] = f2b(a[3]);
  r[4] = f2b(b[0]); r[5] = f2b(b[1]); r[6] = f2b(b[2]); r[7] = f2b(b[3]);
  return r;
}
// swizzled byte address in a 640B-row LDS tile
__device__ __forceinline__ int swz(int row, int b) { return row * 640 + (b ^ ((row & 7) << 4)); }

__global__ __launch_bounds__(256, 2) void lsa_one(
    const float* __restrict__ Qg, const float* __restrict__ Kg,
    const float* __restrict__ Vg, float* __restrict__ Og,
    float* __restrict__ Ag) {
  const int tid = threadIdx.x;
  // XCD-chunked swizzle: XCD x hosts works [128x,128x+128) -> one bh resident
  // per XCD at a time (K+V+Q ~1.5MB fits 4MB L2)
  const int work = ((blockIdx.x & 7) << 7) + (blockIdx.x >> 3);
  const int bh = work >> 5;
  const int q0 = (work & 31) * QBLK;
  int kstart = q0 - WIN; if (kstart < 0) kstart = 0;
  int kend = q0 + QBLK + WIN; if (kend > T_DIM) kend = T_DIM;
  const int KW = kend - kstart;   // 192/256/320
  const int nkt = KW >> 4;

  const float* qptr = Qg + (size_t)bh * (T_DIM * D_DIM);
  const float* kptr = Kg + (size_t)bh * (T_DIM * D_DIM);
  const float* vptr = Vg + (size_t)bh * (T_DIM * D_DIM);
  float* optr = Og + (size_t)bh * (T_DIM * D_DIM);
  float* aptr = Ag + (size_t)bh * ((size_t)T_DIM * T_DIM);

  // LDS: Vt 40KB + P band 40KB = 80KB -> 2 blocks/CU
  __shared__ __align__(16) char Vb[D_DIM * 640];
  __shared__ __align__(16) char Pb[QBLK * 640];

  // ---- stage V transposed: Vt[d][k] bf16 (consumed after the only barrier) ----
  for (int idx = tid; idx < KW * 16; idx += 256) {
    const int r = idx >> 4, c4 = idx & 15;
    f32x4 f = *(const f32x4*)(vptr + (size_t)(kstart + r) * D_DIM + c4 * 4);
    const int d0 = c4 * 4;
    *(short*)(Vb + swz(d0 + 0, r * 2)) = f2b(f[0]);
    *(short*)(Vb + swz(d0 + 1, r * 2)) = f2b(f[1]);
    *(short*)(Vb + swz(d0 + 2, r * 2)) = f2b(f[2]);
    *(short*)(Vb + swz(d0 + 3, r * 2)) = f2b(f[3]);
  }

  const int lane = tid & 63, w = tid >> 6, c = lane & 15, hi = lane >> 4;

  // Q B-frag (swapped QK^T): lane holds Q row q0+w*16+c, d-slices
  const float* qrow = qptr + (size_t)(q0 + w * 16 + c) * D_DIM + 8 * hi;
  const bf16x8 qb0 = cvt8(*(const f32x4*)qrow, *(const f32x4*)(qrow + 4));
  const bf16x8 qb1 = cvt8(*(const f32x4*)(qrow + 32), *(const f32x4*)(qrow + 36));

  // per-wave live tile range
  int klo = q0 + w * 16 - WIN - kstart; if (klo < 0) klo = 0;
  const int kt0 = klo >> 4;
  int kt1 = (q0 + w * 16 + 15 + WIN + 1 - kstart + 15) >> 4; if (kt1 > nkt) kt1 = nkt;
  const int s0 = kt0 >> 1, s1 = (kt1 + 1) >> 1;
  const int nlive = kt1 - kt0;

  // ---- S^T = K Q^T over live tiles: lane (c,hi) owns q-row c, k = 16i+4hi+j ----
  f32x4 acc[ACCT];
#pragma unroll
  for (int i = 0; i < ACCT; ++i) {
    acc[i] = (f32x4){0.f, 0.f, 0.f, 0.f};
    if (i < nlive) {
      const float* kr = kptr + (size_t)(kstart + (kt0 + i) * 16 + c) * D_DIM + 8 * hi;
      const bf16x8 b0 = cvt8(*(const f32x4*)kr, *(const f32x4*)(kr + 4));
      const bf16x8 b1 = cvt8(*(const f32x4*)(kr + 32), *(const f32x4*)(kr + 36));
      acc[i] = __builtin_amdgcn_mfma_f32_16x16x32_bf16(b0, qb0, acc[i], 0, 0, 0);
      acc[i] = __builtin_amdgcn_mfma_f32_16x16x32_bf16(b1, qb1, acc[i], 0, 0, 0);
    }
  }

  // ---- early zero sweep: out-of-band columns, zero data deps; drains under
  //      softmax/P/band (all loads above already issued -> no vmcnt aliasing) ----
  {
    const f32x4 zv = {0.f, 0.f, 0.f, 0.f};
    for (int rr = 0; rr < 16; ++rr) {
      float* dst = aptr + (size_t)(q0 + w * 16 + rr) * T_DIM;
      for (int col = lane * 4; col < kstart; col += 256)
        __builtin_nontemporal_store(zv, (f32x4*)(dst + col));
      for (int col = kend + lane * 4; col < T_DIM; col += 256)
        __builtin_nontemporal_store(zv, (f32x4*)(dst + col));
    }
  }

  // ---- softmax: in-lane over 68 values, then 2 shfls across hi-groups ----
  const int qr = q0 + w * 16 + c;            // this lane's q-row
  const int kb = kstart + 4 * hi;
  float m = NEGBIG;
#pragma unroll
  for (int i = 0; i < ACCT; ++i)
    if (i < nlive) {
#pragma unroll
      for (int j = 0; j < 4; ++j) {
        float s = acc[i][j] * 0.125f;        // 1/sqrt(64)
        const int kcol = kb + (kt0 + i) * 16 + j;
        int dist = qr - kcol; dist = dist < 0 ? -dist : dist;
        s = (dist <= WIN) ? s : NEGBIG;
        acc[i][j] = s;
        m = fmaxf(m, s);
      }
    }
  m = fmaxf(m, __shfl_xor(m, 16));
  m = fmaxf(m, __shfl_xor(m, 32));
  float sum = 0.f;
#pragma unroll
  for (int i = 0; i < ACCT; ++i)
    if (i < nlive) {
#pragma unroll
      for (int j = 0; j < 4; ++j) {
        const float p = __expf(acc[i][j] - m);
        acc[i][j] = p;
        sum += p;
      }
    }
  sum += __shfl_xor(sum, 16);
  sum += __shfl_xor(sum, 32);
  const float inv = 1.f / sum;

  // ---- P(bf16) -> Pb: one ds_write_b64 per live tile ----
  const int prow = w * 16 + c;
#pragma unroll
  for (int i = 0; i < ACCT; ++i)
    if (i < nlive) {
      bf16x4 pk;
#pragma unroll
      for (int j = 0; j < 4; ++j) pk[j] = f2b(acc[i][j] * inv);
      *(bf16x4*)(Pb + swz(prow, 32 * (kt0 + i) + 8 * hi)) = pk;
    }
  {
    const bf16x4 z4 = {0, 0, 0, 0};
    for (int t = 0; t < kt0; ++t) *(bf16x4*)(Pb + swz(prow, 32 * t + 8 * hi)) = z4;
    for (int t = kt1; t < nkt; ++t) *(bf16x4*)(Pb + swz(prow, 32 * t + 8 * hi)) = z4;
  }

  // ---- band sweep: KW cols per row, 1KB-contiguous nt stores from Pb ----
  for (int rr = 0; rr < 16; ++rr) {
    const int r = w * 16 + rr;
    float* dst = aptr + (size_t)(q0 + r) * T_DIM + kstart;
#pragma unroll
    for (int i = 0; i < 2; ++i) {
      const int off = i * 256 + lane * 4;
      if (off < KW) {
        const bf16x4 pv = *(const bf16x4*)(Pb + swz(r, off * 2));
        f32x4 val;
        val[0] = b2f(pv[0]); val[1] = b2f(pv[1]); val[2] = b2f(pv[2]); val[3] = b2f(pv[3]);
        __builtin_nontemporal_store(val, (f32x4*)(dst + off));
      }
    }
  }

  __syncthreads();   // only barrier: Vt ready for PV

  // ---- O = P V ----
  f32x4 ov[4];
#pragma unroll
  for (int dt = 0; dt < 4; ++dt) ov[dt] = (f32x4){0.f, 0.f, 0.f, 0.f};
  for (int s = s0; s < s1; ++s) {
    const bf16x8 pa = *(const bf16x8*)(Pb + swz(w * 16 + c, 64 * s + 16 * hi));
#pragma unroll
    for (int dt = 0; dt < 4; ++dt) {
      const bf16x8 vb = *(const bf16x8*)(Vb + swz(dt * 16 + c, 64 * s + 16 * hi));
      ov[dt] = __builtin_amdgcn_mfma_f32_16x16x32_bf16(pa, vb, ov[dt], 0, 0, 0);
    }
  }

  // ---- O store: bounce through own Pb quarter (wave-private, reads done)
  //      -> 4 contiguous 1KB wave-stores instead of 16 scattered scalars ----
  {
    float* ob = (float*)(Pb + w * 10240);
#pragma unroll
    for (int dt = 0; dt < 4; ++dt)
#pragma unroll
      for (int j = 0; j < 4; ++j)
        ob[(4 * hi + j) * 68 + dt * 16 + c] = ov[dt][j];   // 68-word rows: conflict-free
    float* obase = optr + (size_t)(q0 + w * 16) * D_DIM;
#pragma unroll
    for (int i = 0; i < 4; ++i) {
      const int p = i * 256 + lane * 4;
      const int r = p >> 6, col = p & 63;
      const f32x4 o4 = *(const f32x4*)(ob + r * 68 + col);
      __builtin_nontemporal_store(o4, (f32x4*)(obase + p));
    }
  }
}

extern "C" void kernel_launch(void* const* d_in, const int* in_sizes, int n_in,
                              void* d_out, int out_size, void* d_ws, size_t ws_size,
                              hipStream_t stream) {
  const float* q = (const float*)d_in[0];
  const float* k = (const float*)d_in[1];
  const float* v = (const float*)d_in[2];
  float* out = (float*)d_out;
  float* attn = out + (size_t)2 * 16 * T_DIM * D_DIM;  // output first, then attn
  lsa_one<<<dim3(2 * 16 * (T_DIM / QBLK)), dim3(256), 0, stream>>>(q, k, v, out, attn);
}